// Round 1
// baseline (1111.703 us; speedup 1.0000x reference)
//
#include <hip/hip_runtime.h>
#include <hip/hip_bf16.h>
#include <math.h>

// Problem constants
#define B_  2
#define L_  2048
#define DIM_ 1024
#define DIN_ 2048
#define N_  16
#define DTR_ 64
#define DCONV_ 4
#define BL_ (B_ * L_)        // 4096
#define TWO_DIN_ (2 * DIN_)  // 4096

#define CHUNKS 32
#define LC (L_ / CHUNKS)     // 64

// ---------------------------------------------------------------------------
// Generic fp32 tiled GEMM: C[M,N] = A[M,K] @ B[K,N], all row-major.
// 64x64 tile, BK=16, 256 threads, 4x4 micro-tile per thread.
// ---------------------------------------------------------------------------
#define BM 64
#define BN 64
#define BKK 16

__global__ __launch_bounds__(256) void gemm_f32_nn(const float* __restrict__ A,
                                                   const float* __restrict__ B,
                                                   float* __restrict__ C,
                                                   int M, int N, int K) {
  __shared__ float As[BKK][BM + 1];   // [k][m]
  __shared__ float Bs[BKK][BN + 4];   // [k][n], +4 keeps float4 alignment (272 B rows)
  const int tid = threadIdx.x;
  const int bm = blockIdx.y * BM;
  const int bn = blockIdx.x * BN;
  const int tx = tid & 15;   // n-group
  const int ty = tid >> 4;   // m-group
  float acc[4][4] = {};

  for (int k0 = 0; k0 < K; k0 += BKK) {
    // A tile: 64 rows x 16 k, transposed into As[k][m]
    {
      const int m = tid >> 2;            // 0..63
      const int k = (tid & 3) * 4;       // 0,4,8,12
      const float4 a4 = *reinterpret_cast<const float4*>(
          &A[(size_t)(bm + m) * K + k0 + k]);
      As[k + 0][m] = a4.x;
      As[k + 1][m] = a4.y;
      As[k + 2][m] = a4.z;
      As[k + 3][m] = a4.w;
    }
    // B tile: 16 rows x 64 n
    {
      const int k = tid >> 4;            // 0..15
      const int n = (tid & 15) * 4;      // 0..60
      *reinterpret_cast<float4*>(&Bs[k][n]) =
          *reinterpret_cast<const float4*>(&B[(size_t)(k0 + k) * N + bn + n]);
    }
    __syncthreads();
#pragma unroll
    for (int k = 0; k < BKK; ++k) {
      float a[4], b[4];
#pragma unroll
      for (int i = 0; i < 4; ++i) a[i] = As[k][ty * 4 + i];
#pragma unroll
      for (int j = 0; j < 4; ++j) b[j] = Bs[k][tx * 4 + j];
#pragma unroll
      for (int i = 0; i < 4; ++i)
#pragma unroll
        for (int j = 0; j < 4; ++j)
          acc[i][j] = fmaf(a[i], b[j], acc[i][j]);
    }
    __syncthreads();
  }

#pragma unroll
  for (int i = 0; i < 4; ++i) {
    float4 o4 = make_float4(acc[i][0], acc[i][1], acc[i][2], acc[i][3]);
    *reinterpret_cast<float4*>(&C[(size_t)(bm + ty * 4 + i) * N + bn + tx * 4]) = o4;
  }
}

// ---------------------------------------------------------------------------
// Depthwise causal conv (k=4, left-pad 3) + bias + SiLU.
// xs = xr[:, 0:DIN_] (row stride TWO_DIN_). u[row, d] coalesced over d.
// ---------------------------------------------------------------------------
__global__ __launch_bounds__(256) void conv_silu_kernel(const float* __restrict__ xr,
                                                        const float* __restrict__ conv_w,
                                                        const float* __restrict__ conv_b,
                                                        float* __restrict__ u) {
  const int idx = blockIdx.x * 256 + threadIdx.x;   // over BL_*DIN_
  const int row = idx / DIN_;
  const int d = idx - row * DIN_;
  const int l = row % L_;

  const float w0 = conv_w[d * 4 + 0];
  const float w1 = conv_w[d * 4 + 1];
  const float w2 = conv_w[d * 4 + 2];
  const float w3 = conv_w[d * 4 + 3];

  float s = conv_b[d];
  // xc[l] = sum_{k=0..3} xs[l-3+k] * w[k]
  if (l >= 3) s = fmaf(xr[(size_t)(row - 3) * TWO_DIN_ + d], w0, s);
  if (l >= 2) s = fmaf(xr[(size_t)(row - 2) * TWO_DIN_ + d], w1, s);
  if (l >= 1) s = fmaf(xr[(size_t)(row - 1) * TWO_DIN_ + d], w2, s);
  s = fmaf(xr[(size_t)row * TWO_DIN_ + d], w3, s);

  const float sig = 1.0f / (1.0f + __expf(-s));
  u[(size_t)row * DIN_ + d] = s * sig;
}

// ---------------------------------------------------------------------------
// x_dbl = u @ W_x  : (BL_ x DIN_) @ (DIN_ x 96). Block: 16 rows x 96 cols.
// ---------------------------------------------------------------------------
__global__ __launch_bounds__(256) void xdbl_kernel(const float* __restrict__ u,
                                                   const float* __restrict__ Wx,
                                                   float* __restrict__ xdbl) {
  __shared__ float Us[16][64];
  __shared__ float Ws[64][96 + 1];
  const int tid = threadIdx.x;
  const int r0 = blockIdx.x * 16;
  const int rr = tid >> 4;    // 0..15 local row
  const int cc = tid & 15;    // col group
  float acc[6] = {};

  for (int k0 = 0; k0 < DIN_; k0 += 64) {
    {
      const int r = tid >> 4;
      const int k = (tid & 15) * 4;
      *reinterpret_cast<float4*>(&Us[r][k]) =
          *reinterpret_cast<const float4*>(&u[(size_t)(r0 + r) * DIN_ + k0 + k]);
    }
    for (int i = tid; i < 64 * 96; i += 256) {
      const int k = i / 96;
      const int n = i - k * 96;
      Ws[k][n] = Wx[(size_t)(k0 + k) * 96 + n];
    }
    __syncthreads();
#pragma unroll 8
    for (int k = 0; k < 64; ++k) {
      const float a = Us[rr][k];
#pragma unroll
      for (int jj = 0; jj < 6; ++jj)
        acc[jj] = fmaf(a, Ws[k][cc + 16 * jj], acc[jj]);
    }
    __syncthreads();
  }
#pragma unroll
  for (int jj = 0; jj < 6; ++jj)
    xdbl[(size_t)(r0 + rr) * 96 + cc + 16 * jj] = acc[jj];
}

// ---------------------------------------------------------------------------
// delta = softplus(x_dbl[:, :64] @ W_dt + b_dt) : (BL_ x 64) @ (64 x DIN_)
// Block: 8 rows x 256 cols.
// ---------------------------------------------------------------------------
__global__ __launch_bounds__(256) void delta_kernel(const float* __restrict__ xdbl,
                                                    const float* __restrict__ Wdt,
                                                    const float* __restrict__ bdt,
                                                    float* __restrict__ delta) {
  __shared__ float Xs[8][64];
  const int tid = threadIdx.x;
  const int r0 = blockIdx.x * 8;
  const int d = blockIdx.y * 256 + tid;

  {
    const int i = tid * 2;
    const int r = i >> 6;
    const int k = i & 63;
    Xs[r][k]     = xdbl[(size_t)(r0 + r) * 96 + k];
    Xs[r][k + 1] = xdbl[(size_t)(r0 + r) * 96 + k + 1];
  }
  __syncthreads();

  float acc[8] = {};
  for (int k = 0; k < 64; ++k) {
    const float w = Wdt[(size_t)k * DIN_ + d];
#pragma unroll
    for (int r = 0; r < 8; ++r) acc[r] = fmaf(Xs[r][k], w, acc[r]);
  }
  const float bb = bdt[d];
#pragma unroll
  for (int r = 0; r < 8; ++r) {
    const float v = acc[r] + bb;
    const float sp = fmaxf(v, 0.0f) + log1pf(__expf(-fabsf(v)));
    delta[(size_t)(r0 + r) * DIN_ + d] = sp;
  }
}

// ---------------------------------------------------------------------------
// SSM scan, chunked 3-pass. State h[n] (N_=16) per (b,d). Chunk length LC=64.
// Aggregate layout: [b][c][n][d]  -> (((b*CHUNKS + c)*N_ + n)*DIN_ + d)
// ---------------------------------------------------------------------------
__global__ __launch_bounds__(256) void scan_pass1(const float* __restrict__ delta,
                                                  const float* __restrict__ u,
                                                  const float* __restrict__ xdbl,
                                                  const float* __restrict__ A_log,
                                                  float* __restrict__ Pbuf,
                                                  float* __restrict__ Sbuf) {
  const int d = blockIdx.x * 256 + threadIdx.x;  // 0..DIN_-1
  const int c = blockIdx.y;                       // chunk
  const int b = blockIdx.z;

  float Areg[N_], P[N_], S[N_];
#pragma unroll
  for (int n = 0; n < N_; ++n) {
    Areg[n] = -__expf(A_log[d * N_ + n]);
    P[n] = 1.0f;
    S[n] = 0.0f;
  }

  const int l0 = c * LC;
  for (int l = l0; l < l0 + LC; ++l) {
    const size_t row = (size_t)b * L_ + l;
    const float dv = delta[row * DIN_ + d];
    const float uv = u[row * DIN_ + d];
    const float du = dv * uv;
    const float* __restrict__ bm = &xdbl[row * 96 + 64];  // Bm (wave-uniform)
#pragma unroll
    for (int n = 0; n < N_; ++n) {
      const float a = __expf(dv * Areg[n]);
      P[n] *= a;
      S[n] = fmaf(a, S[n], du * bm[n]);
    }
  }
#pragma unroll
  for (int n = 0; n < N_; ++n) {
    const size_t o = (((size_t)b * CHUNKS + c) * N_ + n) * DIN_ + d;
    Pbuf[o] = P[n];
    Sbuf[o] = S[n];
  }
}

__global__ __launch_bounds__(256) void scan_pass2(const float* __restrict__ Pbuf,
                                                  const float* __restrict__ Sbuf,
                                                  float* __restrict__ Hin) {
  const int d = blockIdx.x * 256 + threadIdx.x;
  const int n = blockIdx.y;
  const int b = blockIdx.z;
  float h = 0.0f;
  for (int c = 0; c < CHUNKS; ++c) {
    const size_t o = (((size_t)b * CHUNKS + c) * N_ + n) * DIN_ + d;
    Hin[o] = h;
    h = fmaf(Pbuf[o], h, Sbuf[o]);
  }
}

__global__ __launch_bounds__(256) void scan_pass3(const float* __restrict__ delta,
                                                  const float* __restrict__ u,
                                                  const float* __restrict__ xdbl,
                                                  const float* __restrict__ A_log,
                                                  const float* __restrict__ Hin,
                                                  const float* __restrict__ Dvec,
                                                  const float* __restrict__ xr,
                                                  float* __restrict__ y) {
  const int d = blockIdx.x * 256 + threadIdx.x;
  const int c = blockIdx.y;
  const int b = blockIdx.z;

  float Areg[N_], h[N_];
#pragma unroll
  for (int n = 0; n < N_; ++n) {
    Areg[n] = -__expf(A_log[d * N_ + n]);
    h[n] = Hin[(((size_t)b * CHUNKS + c) * N_ + n) * DIN_ + d];
  }
  const float Dd = Dvec[d];

  const int l0 = c * LC;
  for (int l = l0; l < l0 + LC; ++l) {
    const size_t row = (size_t)b * L_ + l;
    const float dv = delta[row * DIN_ + d];
    const float uv = u[row * DIN_ + d];
    const float du = dv * uv;
    const float* __restrict__ xrow = &xdbl[row * 96];  // wave-uniform
    float acc = 0.0f;
#pragma unroll
    for (int n = 0; n < N_; ++n) {
      const float a = __expf(dv * Areg[n]);
      h[n] = fmaf(a, h[n], du * xrow[64 + n]);   // Bm
      acc = fmaf(h[n], xrow[80 + n], acc);        // Cm
    }
    acc = fmaf(uv, Dd, acc);
    const float resv = xr[row * TWO_DIN_ + DIN_ + d];
    const float sig = 1.0f / (1.0f + __expf(-resv));
    // y aliases delta: delta[row*DIN_+d] was read above in THIS iteration/thread.
    y[row * DIN_ + d] = acc * (resv * sig);
  }
}

// ---------------------------------------------------------------------------
extern "C" void kernel_launch(void* const* d_in, const int* in_sizes, int n_in,
                              void* d_out, int out_size, void* d_ws, size_t ws_size,
                              hipStream_t stream) {
  const float* x      = (const float*)d_in[0];
  const float* W_in   = (const float*)d_in[1];
  const float* conv_w = (const float*)d_in[2];
  const float* conv_b = (const float*)d_in[3];
  const float* W_x    = (const float*)d_in[4];
  const float* W_dt   = (const float*)d_in[5];
  const float* b_dt   = (const float*)d_in[6];
  const float* W_out  = (const float*)d_in[7];
  const float* A_log  = (const float*)d_in[8];
  const float* Dv     = (const float*)d_in[9];
  float* out = (float*)d_out;

  char* ws = (char*)d_ws;
  // Workspace layout (bytes):
  float* xr    = (float*)(ws);                       // 4096*4096*4 = 64 MiB
  float* u     = (float*)(ws + 67108864);            // 4096*2048*4 = 32 MiB
  float* xdbl  = (float*)(ws + 100663296);           // 4096*96*4   = 1.5 MiB
  float* delta = (float*)(ws + 102236160);           // 4096*2048*4 = 32 MiB
  float* Pbuf  = (float*)(ws + 135790592);           // 2*32*16*2048*4 = 8 MiB
  float* Sbuf  = (float*)(ws + 144179200);           // 8 MiB
  float* Hin   = (float*)(ws + 152567808);           // 8 MiB
  float* y     = delta;  // alias: pass3 reads delta[i] before writing y[i] (same thread)

  // 1. xr = x @ W_in   (4096 x 1024 x 4096)
  gemm_f32_nn<<<dim3(TWO_DIN_ / BN, BL_ / BM), 256, 0, stream>>>(
      x, W_in, xr, BL_, TWO_DIN_, DIM_);

  // 2. u = silu(depthwise_causal_conv(xs) + conv_b)
  conv_silu_kernel<<<(BL_ * DIN_) / 256, 256, 0, stream>>>(xr, conv_w, conv_b, u);

  // 3. x_dbl = u @ W_x   (4096 x 2048 x 96)
  xdbl_kernel<<<BL_ / 16, 256, 0, stream>>>(u, W_x, xdbl);

  // 4. delta = softplus(x_dbl[:, :64] @ W_dt + b_dt)
  delta_kernel<<<dim3(BL_ / 8, DIN_ / 256), 256, 0, stream>>>(xdbl, W_dt, b_dt, delta);

  // 5-7. chunked SSM scan + y gate
  scan_pass1<<<dim3(DIN_ / 256, CHUNKS, B_), 256, 0, stream>>>(
      delta, u, xdbl, A_log, Pbuf, Sbuf);
  scan_pass2<<<dim3(DIN_ / 256, N_, B_), 256, 0, stream>>>(Pbuf, Sbuf, Hin);
  scan_pass3<<<dim3(DIN_ / 256, CHUNKS, B_), 256, 0, stream>>>(
      delta, u, xdbl, A_log, Hin, Dv, xr, y);

  // 8. out = y @ W_out   (4096 x 2048 x 1024)
  gemm_f32_nn<<<dim3(DIM_ / BN, BL_ / BM), 256, 0, stream>>>(
      y, W_out, out, BL_, DIM_, DIN_);
}

// Round 2
// 477.325 us; speedup vs baseline: 2.3290x; 2.3290x over previous
//
#include <hip/hip_runtime.h>
#include <hip/hip_bf16.h>
#include <math.h>

// Problem constants
#define B_  2
#define L_  2048
#define DIM_ 1024
#define DIN_ 2048
#define N_  16
#define DTR_ 64
#define DCONV_ 4
#define BL_ (B_ * L_)        // 4096
#define TWO_DIN_ (2 * DIN_)  // 4096

#define CHUNKS 32
#define LC (L_ / CHUNKS)     // 64

typedef __attribute__((ext_vector_type(8))) short short8;     // 8 bf16 = 4 VGPRs
typedef __attribute__((ext_vector_type(8))) unsigned short ushort8;
typedef __attribute__((ext_vector_type(4))) float f32x4;

__device__ __forceinline__ unsigned short f2bf(float f) {     // RNE fp32->bf16
  unsigned int u = __float_as_uint(f);
  u += 0x7fffu + ((u >> 16) & 1u);
  return (unsigned short)(u >> 16);
}
__device__ __forceinline__ float bf2f(unsigned short h) {
  return __uint_as_float((unsigned int)h << 16);
}

// async 16B global->LDS (wave-uniform LDS base + lane*16 scatter by HW)
typedef const __attribute__((address_space(1))) void gvoid_t;
typedef __attribute__((address_space(3))) void svoid_t;
__device__ __forceinline__ void gld16(const void* g, void* l) {
  __builtin_amdgcn_global_load_lds((gvoid_t*)g, (svoid_t*)l, 16, 0, 0);
}

// ---------------------------------------------------------------------------
// bf16 MFMA GEMM: C[M][N] = A[M][K] @ Bt[N][K]^T  (both operands K-contiguous)
// 128x128 tile, BK=32, 256 threads (4 waves), each wave 64x64 via 4x4 MFMA
// 16x16x32 tiles. m97 structure: global_load_lds w=16, 2-barrier K-loop.
// ---------------------------------------------------------------------------
template <bool OUT_BF16>
__global__ __launch_bounds__(256) void gemm_bf16_mfma(
    const unsigned short* __restrict__ A,   // [M][K] bf16
    const unsigned short* __restrict__ Bt,  // [N][K] bf16
    void* __restrict__ Cout, int M, int N, int K) {
  __shared__ unsigned short As[128 * 32];   // [m][k], 64B rows, 8 KB
  __shared__ unsigned short Bs[128 * 32];   // [n][k]
  const int tid  = threadIdx.x;
  const int wave = tid >> 6;
  const int lane = tid & 63;
  const int bm = blockIdx.y * 128;
  const int bn = blockIdx.x * 128;

  const int wm = (wave & 1) * 64;
  const int wn = (wave >> 1) * 64;
  const int fm = lane & 15;        // fragment row (A) / row (B=n)
  const int quad = lane >> 4;      // 0..3
  const int fk = quad * 8;         // fragment k element offset

  // staging: each wave stages 2 chunks of 16 rows (1024 B) per matrix.
  const int srow = lane >> 2;          // 0..15 row within chunk
  const int skb  = (lane & 3) * 16;    // byte offset within 64B row
  const size_t krow = (size_t)K * 2;   // bytes per K-row

  const char* Ag = (const char*)A + (size_t)(bm + wave * 16 + srow) * krow + skb;
  const char* Bg = (const char*)Bt + (size_t)(bn + wave * 16 + srow) * krow + skb;
  char* lA0 = (char*)As + wave * 1024;
  char* lA1 = (char*)As + 4096 + wave * 1024;
  char* lB0 = (char*)Bs + wave * 1024;
  char* lB1 = (char*)Bs + 4096 + wave * 1024;

  f32x4 acc[4][4] = {};

  for (int k0 = 0; k0 < K; k0 += 32) {
    const size_t kb = (size_t)k0 * 2;
    gld16(Ag + kb, lA0);
    gld16(Ag + 64 * krow + kb, lA1);
    gld16(Bg + kb, lB0);
    gld16(Bg + 64 * krow + kb, lB1);
    __syncthreads();   // drains vmcnt (global_load_lds) + lgkm before barrier

    short8 a[4], b[4];
#pragma unroll
    for (int i = 0; i < 4; ++i) {
      a[i] = *reinterpret_cast<const short8*>(&As[(wm + i * 16 + fm) * 32 + fk]);
      b[i] = *reinterpret_cast<const short8*>(&Bs[(wn + i * 16 + fm) * 32 + fk]);
    }
#pragma unroll
    for (int i = 0; i < 4; ++i)
#pragma unroll
      for (int j = 0; j < 4; ++j)
        acc[i][j] = __builtin_amdgcn_mfma_f32_16x16x32_bf16(a[i], b[j], acc[i][j], 0, 0, 0);
    __syncthreads();
  }

  // epilogue: C/D map col=lane&15, row=quad*4+reg  [m89/m91 verified]
  const int r0 = quad * 4;
#pragma unroll
  for (int i = 0; i < 4; ++i) {
    const int gm = bm + wm + i * 16 + r0;
#pragma unroll
    for (int j = 0; j < 4; ++j) {
      const int gn = bn + wn + j * 16 + fm;
#pragma unroll
      for (int r = 0; r < 4; ++r) {
        if (OUT_BF16)
          ((unsigned short*)Cout)[(size_t)(gm + r) * N + gn] = f2bf(acc[i][j][r]);
        else
          ((float*)Cout)[(size_t)(gm + r) * N + gn] = acc[i][j][r];
      }
    }
  }
}

// ---------------------------------------------------------------------------
// fp32 -> bf16 cast, 8 elems/thread
// ---------------------------------------------------------------------------
__global__ __launch_bounds__(256) void cast_bf16_kernel(const float* __restrict__ in,
                                                        unsigned short* __restrict__ out) {
  const size_t i = ((size_t)blockIdx.x * 256 + threadIdx.x) * 8;
  const float4 v0 = *reinterpret_cast<const float4*>(in + i);
  const float4 v1 = *reinterpret_cast<const float4*>(in + i + 4);
  ushort8 o;
  o[0] = f2bf(v0.x); o[1] = f2bf(v0.y); o[2] = f2bf(v0.z); o[3] = f2bf(v0.w);
  o[4] = f2bf(v1.x); o[5] = f2bf(v1.y); o[6] = f2bf(v1.z); o[7] = f2bf(v1.w);
  *reinterpret_cast<ushort8*>(out + i) = o;
}

// ---------------------------------------------------------------------------
// transpose + cast: in fp32 [rows][cols] -> out bf16 [cols][rows]
// ---------------------------------------------------------------------------
__global__ __launch_bounds__(256) void transpose_cast_kernel(
    const float* __restrict__ in, unsigned short* __restrict__ out,
    int rows, int cols) {
  __shared__ float tile[32][33];
  const int tx = threadIdx.x & 31;
  const int ty = threadIdx.x >> 5;   // 0..7
  const int c0 = blockIdx.x * 32;
  const int r0 = blockIdx.y * 32;
#pragma unroll
  for (int i = 0; i < 32; i += 8)
    tile[ty + i][tx] = in[(size_t)(r0 + ty + i) * cols + c0 + tx];
  __syncthreads();
#pragma unroll
  for (int i = 0; i < 32; i += 8)
    out[(size_t)(c0 + ty + i) * rows + r0 + tx] = f2bf(tile[tx][ty + i]);
}

// ---------------------------------------------------------------------------
// Depthwise causal conv (k=4, left-pad 3) + bias + SiLU. xs = xrb[:, 0:DIN_]
// (bf16, row stride TWO_DIN_). u fp32.
// ---------------------------------------------------------------------------
__global__ __launch_bounds__(256) void conv_silu_kernel(const unsigned short* __restrict__ xrb,
                                                        const float* __restrict__ conv_w,
                                                        const float* __restrict__ conv_b,
                                                        float* __restrict__ u) {
  const int idx = blockIdx.x * 256 + threadIdx.x;   // over BL_*DIN_
  const int row = idx / DIN_;
  const int d = idx - row * DIN_;
  const int l = row % L_;

  const float w0 = conv_w[d * 4 + 0];
  const float w1 = conv_w[d * 4 + 1];
  const float w2 = conv_w[d * 4 + 2];
  const float w3 = conv_w[d * 4 + 3];

  float s = conv_b[d];
  if (l >= 3) s = fmaf(bf2f(xrb[(size_t)(row - 3) * TWO_DIN_ + d]), w0, s);
  if (l >= 2) s = fmaf(bf2f(xrb[(size_t)(row - 2) * TWO_DIN_ + d]), w1, s);
  if (l >= 1) s = fmaf(bf2f(xrb[(size_t)(row - 1) * TWO_DIN_ + d]), w2, s);
  s = fmaf(bf2f(xrb[(size_t)row * TWO_DIN_ + d]), w3, s);

  const float sig = 1.0f / (1.0f + __expf(-s));
  u[(size_t)row * DIN_ + d] = s * sig;
}

// ---------------------------------------------------------------------------
// x_dbl = u @ W_x  : (BL_ x DIN_) @ (DIN_ x 96). Block: 16 rows x 96 cols.
// ---------------------------------------------------------------------------
__global__ __launch_bounds__(256) void xdbl_kernel(const float* __restrict__ u,
                                                   const float* __restrict__ Wx,
                                                   float* __restrict__ xdbl) {
  __shared__ float Us[16][64];
  __shared__ float Ws[64][96 + 1];
  const int tid = threadIdx.x;
  const int r0 = blockIdx.x * 16;
  const int rr = tid >> 4;
  const int cc = tid & 15;
  float acc[6] = {};

  for (int k0 = 0; k0 < DIN_; k0 += 64) {
    {
      const int r = tid >> 4;
      const int k = (tid & 15) * 4;
      *reinterpret_cast<float4*>(&Us[r][k]) =
          *reinterpret_cast<const float4*>(&u[(size_t)(r0 + r) * DIN_ + k0 + k]);
    }
    for (int i = tid; i < 64 * 96; i += 256) {
      const int k = i / 96;
      const int n = i - k * 96;
      Ws[k][n] = Wx[(size_t)(k0 + k) * 96 + n];
    }
    __syncthreads();
#pragma unroll 8
    for (int k = 0; k < 64; ++k) {
      const float a = Us[rr][k];
#pragma unroll
      for (int jj = 0; jj < 6; ++jj)
        acc[jj] = fmaf(a, Ws[k][cc + 16 * jj], acc[jj]);
    }
    __syncthreads();
  }
#pragma unroll
  for (int jj = 0; jj < 6; ++jj)
    xdbl[(size_t)(r0 + rr) * 96 + cc + 16 * jj] = acc[jj];
}

// ---------------------------------------------------------------------------
// delta = softplus(x_dbl[:, :64] @ W_dt + b_dt)
// ---------------------------------------------------------------------------
__global__ __launch_bounds__(256) void delta_kernel(const float* __restrict__ xdbl,
                                                    const float* __restrict__ Wdt,
                                                    const float* __restrict__ bdt,
                                                    float* __restrict__ delta) {
  __shared__ float Xs[8][64];
  const int tid = threadIdx.x;
  const int r0 = blockIdx.x * 8;
  const int d = blockIdx.y * 256 + tid;

  {
    const int i = tid * 2;
    const int r = i >> 6;
    const int k = i & 63;
    Xs[r][k]     = xdbl[(size_t)(r0 + r) * 96 + k];
    Xs[r][k + 1] = xdbl[(size_t)(r0 + r) * 96 + k + 1];
  }
  __syncthreads();

  float acc[8] = {};
  for (int k = 0; k < 64; ++k) {
    const float w = Wdt[(size_t)k * DIN_ + d];
#pragma unroll
    for (int r = 0; r < 8; ++r) acc[r] = fmaf(Xs[r][k], w, acc[r]);
  }
  const float bb = bdt[d];
#pragma unroll
  for (int r = 0; r < 8; ++r) {
    const float v = acc[r] + bb;
    const float sp = fmaxf(v, 0.0f) + log1pf(__expf(-fabsf(v)));
    delta[(size_t)(r0 + r) * DIN_ + d] = sp;
  }
}

// ---------------------------------------------------------------------------
// SSM scan, chunked 3-pass. Aggregates: [b][c][n][d]
// ---------------------------------------------------------------------------
__global__ __launch_bounds__(256) void scan_pass1(const float* __restrict__ delta,
                                                  const float* __restrict__ u,
                                                  const float* __restrict__ xdbl,
                                                  const float* __restrict__ A_log,
                                                  float* __restrict__ Pbuf,
                                                  float* __restrict__ Sbuf) {
  const int d = blockIdx.x * 256 + threadIdx.x;
  const int c = blockIdx.y;
  const int b = blockIdx.z;

  float Areg[N_], P[N_], S[N_];
#pragma unroll
  for (int n = 0; n < N_; ++n) {
    Areg[n] = -__expf(A_log[d * N_ + n]);
    P[n] = 1.0f;
    S[n] = 0.0f;
  }

  const int l0 = c * LC;
  for (int l = l0; l < l0 + LC; ++l) {
    const size_t row = (size_t)b * L_ + l;
    const float dv = delta[row * DIN_ + d];
    const float uv = u[row * DIN_ + d];
    const float du = dv * uv;
    const float* __restrict__ bm = &xdbl[row * 96 + 64];
#pragma unroll
    for (int n = 0; n < N_; ++n) {
      const float a = __expf(dv * Areg[n]);
      P[n] *= a;
      S[n] = fmaf(a, S[n], du * bm[n]);
    }
  }
#pragma unroll
  for (int n = 0; n < N_; ++n) {
    const size_t o = (((size_t)b * CHUNKS + c) * N_ + n) * DIN_ + d;
    Pbuf[o] = P[n];
    Sbuf[o] = S[n];
  }
}

__global__ __launch_bounds__(256) void scan_pass2(const float* __restrict__ Pbuf,
                                                  const float* __restrict__ Sbuf,
                                                  float* __restrict__ Hin) {
  const int d = blockIdx.x * 256 + threadIdx.x;
  const int n = blockIdx.y;
  const int b = blockIdx.z;
  float h = 0.0f;
  for (int c = 0; c < CHUNKS; ++c) {
    const size_t o = (((size_t)b * CHUNKS + c) * N_ + n) * DIN_ + d;
    Hin[o] = h;
    h = fmaf(Pbuf[o], h, Sbuf[o]);
  }
}

__global__ __launch_bounds__(256) void scan_pass3(const float* __restrict__ delta,
                                                  const float* __restrict__ u,
                                                  const float* __restrict__ xdbl,
                                                  const float* __restrict__ A_log,
                                                  const float* __restrict__ Hin,
                                                  const float* __restrict__ Dvec,
                                                  const unsigned short* __restrict__ xrb,
                                                  unsigned short* __restrict__ yb) {
  const int d = blockIdx.x * 256 + threadIdx.x;
  const int c = blockIdx.y;
  const int b = blockIdx.z;

  float Areg[N_], h[N_];
#pragma unroll
  for (int n = 0; n < N_; ++n) {
    Areg[n] = -__expf(A_log[d * N_ + n]);
    h[n] = Hin[(((size_t)b * CHUNKS + c) * N_ + n) * DIN_ + d];
  }
  const float Dd = Dvec[d];

  const int l0 = c * LC;
  for (int l = l0; l < l0 + LC; ++l) {
    const size_t row = (size_t)b * L_ + l;
    const float dv = delta[row * DIN_ + d];
    const float uv = u[row * DIN_ + d];
    const float du = dv * uv;
    const float* __restrict__ xrow = &xdbl[row * 96];
    float acc = 0.0f;
#pragma unroll
    for (int n = 0; n < N_; ++n) {
      const float a = __expf(dv * Areg[n]);
      h[n] = fmaf(a, h[n], du * xrow[64 + n]);   // Bm
      acc = fmaf(h[n], xrow[80 + n], acc);        // Cm
    }
    acc = fmaf(uv, Dd, acc);
    const float resv = bf2f(xrb[row * TWO_DIN_ + DIN_ + d]);
    const float sig = 1.0f / (1.0f + __expf(-resv));
    yb[row * DIN_ + d] = f2bf(acc * (resv * sig));
  }
}

// ---------------------------------------------------------------------------
extern "C" void kernel_launch(void* const* d_in, const int* in_sizes, int n_in,
                              void* d_out, int out_size, void* d_ws, size_t ws_size,
                              hipStream_t stream) {
  const float* x      = (const float*)d_in[0];
  const float* W_in   = (const float*)d_in[1];
  const float* conv_w = (const float*)d_in[2];
  const float* conv_b = (const float*)d_in[3];
  const float* W_x    = (const float*)d_in[4];
  const float* W_dt   = (const float*)d_in[5];
  const float* b_dt   = (const float*)d_in[6];
  const float* W_out  = (const float*)d_in[7];
  const float* A_log  = (const float*)d_in[8];
  const float* Dv     = (const float*)d_in[9];
  float* out = (float*)d_out;

  char* ws = (char*)d_ws;
  // Workspace layout (bytes), total 148.4 MB (< 161 MB known-good):
  unsigned short* xrb   = (unsigned short*)(ws);                 // 4096x4096 bf16, 32 MB
  float* u              = (float*)(ws + 33554432);               // 32 MB
  float* delta          = (float*)(ws + 67108864);               // 32 MB
  float* xdbl           = (float*)(ws + 100663296);              // 1.5 MB
  float* Pbuf           = (float*)(ws + 102236160);              // 8 MB
  float* Sbuf           = (float*)(ws + 110624768);              // 8 MB
  float* Hin            = (float*)(ws + 119013376);              // 8 MB
  unsigned short* xb    = (unsigned short*)(ws + 127401984);     // x bf16, 8 MB
  unsigned short* WinT  = (unsigned short*)(ws + 135790592);     // [4096][1024] bf16, 8 MB
  unsigned short* WoutT = (unsigned short*)(ws + 144179200);     // [1024][2048] bf16, 4 MB
  unsigned short* yb    = (unsigned short*)(ws + 102236160);     // aliases Pbuf+Sbuf (dead after pass2), 16 MB

  // 0. casts / transposes
  cast_bf16_kernel<<<(BL_ * DIM_) / (256 * 8), 256, 0, stream>>>(x, xb);
  transpose_cast_kernel<<<dim3(TWO_DIN_ / 32, DIM_ / 32), 256, 0, stream>>>(
      W_in, WinT, DIM_, TWO_DIN_);
  transpose_cast_kernel<<<dim3(DIM_ / 32, DIN_ / 32), 256, 0, stream>>>(
      W_out, WoutT, DIN_, DIM_);

  // 1. xrb = bf16( x @ W_in )   (4096 x 4096 x 1024), MFMA
  gemm_bf16_mfma<true><<<dim3(TWO_DIN_ / 128, BL_ / 128), 256, 0, stream>>>(
      xb, WinT, xrb, BL_, TWO_DIN_, DIM_);

  // 2. u = silu(conv(xs) + b)
  conv_silu_kernel<<<(BL_ * DIN_) / 256, 256, 0, stream>>>(xrb, conv_w, conv_b, u);

  // 3. x_dbl = u @ W_x
  xdbl_kernel<<<BL_ / 16, 256, 0, stream>>>(u, W_x, xdbl);

  // 4. delta = softplus(x_dbl[:, :64] @ W_dt + b_dt)
  delta_kernel<<<dim3(BL_ / 8, DIN_ / 256), 256, 0, stream>>>(xdbl, W_dt, b_dt, delta);

  // 5-7. chunked SSM scan + gate, y written as bf16
  scan_pass1<<<dim3(DIN_ / 256, CHUNKS, B_), 256, 0, stream>>>(
      delta, u, xdbl, A_log, Pbuf, Sbuf);
  scan_pass2<<<dim3(DIN_ / 256, N_, B_), 256, 0, stream>>>(Pbuf, Sbuf, Hin);
  scan_pass3<<<dim3(DIN_ / 256, CHUNKS, B_), 256, 0, stream>>>(
      delta, u, xdbl, A_log, Hin, Dv, xrb, yb);

  // 8. out = y @ W_out   (4096 x 1024 x 2048), MFMA, fp32 out
  gemm_bf16_mfma<false><<<dim3(DIM_ / 128, BL_ / 128), 256, 0, stream>>>(
      yb, WoutT, out, BL_, DIM_, DIN_);
}

// Round 3
// 373.605 us; speedup vs baseline: 2.9756x; 1.2776x over previous
//
#include <hip/hip_runtime.h>
#include <hip/hip_bf16.h>
#include <math.h>

// Problem constants
#define B_  2
#define L_  2048
#define DIM_ 1024
#define DIN_ 2048
#define N_  16
#define DTR_ 64
#define DCONV_ 4
#define BL_ (B_ * L_)        // 4096
#define TWO_DIN_ (2 * DIN_)  // 4096

#define CHUNKS 32
#define LC (L_ / CHUNKS)     // 64

typedef __attribute__((ext_vector_type(8))) short short8;     // 8 bf16 = 4 VGPRs
typedef __attribute__((ext_vector_type(8))) unsigned short ushort8;
typedef __attribute__((ext_vector_type(4))) float f32x4;

__device__ __forceinline__ unsigned short f2bf(float f) {     // RNE fp32->bf16
  unsigned int u = __float_as_uint(f);
  u += 0x7fffu + ((u >> 16) & 1u);
  return (unsigned short)(u >> 16);
}
__device__ __forceinline__ float bf2f(unsigned short h) {
  return __uint_as_float((unsigned int)h << 16);
}

// async 16B global->LDS (wave-uniform LDS base + lane*16 scatter by HW)
typedef const __attribute__((address_space(1))) void gvoid_t;
typedef __attribute__((address_space(3))) void svoid_t;
__device__ __forceinline__ void gld16(const void* g, void* l) {
  __builtin_amdgcn_global_load_lds((gvoid_t*)g, (svoid_t*)l, 16, 0, 0);
}

// ---------------------------------------------------------------------------
// bf16 MFMA GEMM: C[M][N] = A[M][kz*Klen:+Klen] @ Bt[N][kz*Klen:+Klen]^T
// 128x128 tile, BK=32, 256 threads (4 waves). m97 structure.
// gridDim.z = #K-splits; fp32 output goes to C + z*M*N (partials).
// ---------------------------------------------------------------------------
template <bool OUT_BF16>
__global__ __launch_bounds__(256) void gemm_bf16_mfma(
    const unsigned short* __restrict__ A,   // [M][lda] bf16
    const unsigned short* __restrict__ Bt,  // [N][ldb] bf16
    void* __restrict__ Cout, int M, int N, int Klen, int lda, int ldb) {
  __shared__ unsigned short As[128 * 32];   // [m][k], 64B rows, 8 KB
  __shared__ unsigned short Bs[128 * 32];   // [n][k]
  const int tid  = threadIdx.x;
  const int wave = tid >> 6;
  const int lane = tid & 63;
  const int bm = blockIdx.y * 128;
  const int bn = blockIdx.x * 128;
  const int kz = blockIdx.z;

  const int wm = (wave & 1) * 64;
  const int wn = (wave >> 1) * 64;
  const int fm = lane & 15;
  const int quad = lane >> 4;
  const int fk = quad * 8;

  const int srow = lane >> 2;          // 0..15 row within 16-row chunk
  const int skb  = (lane & 3) * 16;    // byte offset within 64B LDS row
  const size_t krowA = (size_t)lda * 2;
  const size_t krowB = (size_t)ldb * 2;
  const size_t kzoff = (size_t)kz * Klen * 2;

  const char* Ag = (const char*)A + (size_t)(bm + wave * 16 + srow) * krowA + kzoff + skb;
  const char* Bg = (const char*)Bt + (size_t)(bn + wave * 16 + srow) * krowB + kzoff + skb;
  char* lA0 = (char*)As + wave * 1024;
  char* lA1 = (char*)As + 4096 + wave * 1024;
  char* lB0 = (char*)Bs + wave * 1024;
  char* lB1 = (char*)Bs + 4096 + wave * 1024;

  f32x4 acc[4][4] = {};

  for (int k0 = 0; k0 < Klen; k0 += 32) {
    const size_t kb = (size_t)k0 * 2;
    gld16(Ag + kb, lA0);
    gld16(Ag + 64 * krowA + kb, lA1);
    gld16(Bg + kb, lB0);
    gld16(Bg + 64 * krowB + kb, lB1);
    __syncthreads();

    short8 a[4], b[4];
#pragma unroll
    for (int i = 0; i < 4; ++i) {
      a[i] = *reinterpret_cast<const short8*>(&As[(wm + i * 16 + fm) * 32 + fk]);
      b[i] = *reinterpret_cast<const short8*>(&Bs[(wn + i * 16 + fm) * 32 + fk]);
    }
#pragma unroll
    for (int i = 0; i < 4; ++i)
#pragma unroll
      for (int j = 0; j < 4; ++j)
        acc[i][j] = __builtin_amdgcn_mfma_f32_16x16x32_bf16(a[i], b[j], acc[i][j], 0, 0, 0);
    __syncthreads();
  }

  // epilogue: C/D map col=lane&15, row=quad*4+reg
  const int r0 = quad * 4;
#pragma unroll
  for (int i = 0; i < 4; ++i) {
    const int gm = bm + wm + i * 16 + r0;
#pragma unroll
    for (int j = 0; j < 4; ++j) {
      const int gn = bn + wn + j * 16 + fm;
#pragma unroll
      for (int r = 0; r < 4; ++r) {
        if (OUT_BF16)
          ((unsigned short*)Cout)[(size_t)(gm + r) * N + gn] = f2bf(acc[i][j][r]);
        else
          ((float*)Cout)[(size_t)kz * M * N + (size_t)(gm + r) * N + gn] = acc[i][j][r];
      }
    }
  }
}

// ---------------------------------------------------------------------------
// out = p[0] + p[1]  (gemm2 split-K=2 combine), float4
// ---------------------------------------------------------------------------
__global__ __launch_bounds__(256) void add_out_kernel(const float* __restrict__ p,
                                                      float* __restrict__ out) {
  const size_t i = ((size_t)blockIdx.x * 256 + threadIdx.x) * 4;
  const float4 a = *reinterpret_cast<const float4*>(p + i);
  const float4 b = *reinterpret_cast<const float4*>(p + (size_t)BL_ * DIM_ + i);
  float4 o = make_float4(a.x + b.x, a.y + b.y, a.z + b.z, a.w + b.w);
  *reinterpret_cast<float4*>(out + i) = o;
}

// ---------------------------------------------------------------------------
// x_dbl MFMA split-K: Pxd[kz][M=4096][96] = ub[M][kz*256:+256] @ WxT[96][...]^T
// tile 64m x 96n, BK=32, 256 threads (4 waves; wave w = m-subtile w, all 6 n-tiles)
// grid (64, 8)
// ---------------------------------------------------------------------------
__global__ __launch_bounds__(256) void xdbl_mfma(const unsigned short* __restrict__ ub,
                                                 const unsigned short* __restrict__ WxT,
                                                 float* __restrict__ Pxd) {
  __shared__ unsigned short As[64 * 32];   // 4 KB, [m][k] 64B rows
  __shared__ unsigned short Bs[96 * 32];   // 6 KB, [n][k]
  const int tid  = threadIdx.x;
  const int wave = tid >> 6;
  const int lane = tid & 63;
  const int bm = blockIdx.x * 64;
  const int kbase = blockIdx.y * 256;

  const int fm = lane & 15;
  const int quad = lane >> 4;
  const int fk = quad * 8;
  const int srow = lane >> 2;
  const int skb = (lane & 3) * 16;
  const size_t krow = (size_t)DIN_ * 2;

  const char* Ag = (const char*)ub + (size_t)(bm + wave * 16 + srow) * krow
                   + (size_t)kbase * 2 + skb;
  const char* Bg0 = (const char*)WxT + (size_t)(wave * 16 + srow) * krow
                    + (size_t)kbase * 2 + skb;
  const char* Bg1 = (const char*)WxT + (size_t)((wave + 4) * 16 + srow) * krow
                    + (size_t)kbase * 2 + skb;   // only waves 0,1
  char* lA  = (char*)As + wave * 1024;
  char* lB0 = (char*)Bs + wave * 1024;
  char* lB1 = (char*)Bs + (wave + 4) * 1024;

  f32x4 acc[6] = {};

  for (int kk = 0; kk < 8; ++kk) {
    const size_t kb = (size_t)kk * 64;   // 32 elems * 2B
    gld16(Ag + kb, lA);
    gld16(Bg0 + kb, lB0);
    if (wave < 2) gld16(Bg1 + kb, lB1);
    __syncthreads();

    const short8 a = *reinterpret_cast<const short8*>(&As[(wave * 16 + fm) * 32 + fk]);
#pragma unroll
    for (int nt = 0; nt < 6; ++nt) {
      const short8 b = *reinterpret_cast<const short8*>(&Bs[(nt * 16 + fm) * 32 + fk]);
      acc[nt] = __builtin_amdgcn_mfma_f32_16x16x32_bf16(a, b, acc[nt], 0, 0, 0);
    }
    __syncthreads();
  }

  float* P = Pxd + (size_t)blockIdx.y * (BL_ * 96);
  const int gm0 = bm + wave * 16 + quad * 4;
#pragma unroll
  for (int nt = 0; nt < 6; ++nt) {
    const int gn = nt * 16 + fm;
#pragma unroll
    for (int r = 0; r < 4; ++r)
      P[(size_t)(gm0 + r) * 96 + gn] = acc[nt][r];
  }
}

// xdbl[i] = sum over 8 K-splits of Pxd[s][i]
__global__ __launch_bounds__(256) void reduce_xdbl(const float* __restrict__ Pxd,
                                                   float* __restrict__ xdbl) {
  const size_t i = ((size_t)blockIdx.x * 256 + threadIdx.x) * 4;
  float4 s = *reinterpret_cast<const float4*>(Pxd + i);
#pragma unroll
  for (int k = 1; k < 8; ++k) {
    const float4 v = *reinterpret_cast<const float4*>(Pxd + (size_t)k * (BL_ * 96) + i);
    s.x += v.x; s.y += v.y; s.z += v.z; s.w += v.w;
  }
  *reinterpret_cast<float4*>(xdbl + i) = s;
}

// ---------------------------------------------------------------------------
// fp32 -> bf16 cast, 8 elems/thread
// ---------------------------------------------------------------------------
__global__ __launch_bounds__(256) void cast_bf16_kernel(const float* __restrict__ in,
                                                        unsigned short* __restrict__ out) {
  const size_t i = ((size_t)blockIdx.x * 256 + threadIdx.x) * 8;
  const float4 v0 = *reinterpret_cast<const float4*>(in + i);
  const float4 v1 = *reinterpret_cast<const float4*>(in + i + 4);
  ushort8 o;
  o[0] = f2bf(v0.x); o[1] = f2bf(v0.y); o[2] = f2bf(v0.z); o[3] = f2bf(v0.w);
  o[4] = f2bf(v1.x); o[5] = f2bf(v1.y); o[6] = f2bf(v1.z); o[7] = f2bf(v1.w);
  *reinterpret_cast<ushort8*>(out + i) = o;
}

// ---------------------------------------------------------------------------
// transpose + cast: in fp32 [rows][cols] -> out bf16 [cols][rows]
// ---------------------------------------------------------------------------
__global__ __launch_bounds__(256) void transpose_cast_kernel(
    const float* __restrict__ in, unsigned short* __restrict__ out,
    int rows, int cols) {
  __shared__ float tile[32][33];
  const int tx = threadIdx.x & 31;
  const int ty = threadIdx.x >> 5;
  const int c0 = blockIdx.x * 32;
  const int r0 = blockIdx.y * 32;
#pragma unroll
  for (int i = 0; i < 32; i += 8)
    tile[ty + i][tx] = in[(size_t)(r0 + ty + i) * cols + c0 + tx];
  __syncthreads();
#pragma unroll
  for (int i = 0; i < 32; i += 8)
    out[(size_t)(c0 + ty + i) * rows + r0 + tx] = f2bf(tile[tx][ty + i]);
}

// ---------------------------------------------------------------------------
// Depthwise causal conv (k=4) + bias + SiLU. Writes u fp32 AND ub bf16.
// ---------------------------------------------------------------------------
__global__ __launch_bounds__(256) void conv_silu_kernel(const unsigned short* __restrict__ xrb,
                                                        const float* __restrict__ conv_w,
                                                        const float* __restrict__ conv_b,
                                                        float* __restrict__ u,
                                                        unsigned short* __restrict__ ub) {
  const int idx = blockIdx.x * 256 + threadIdx.x;
  const int row = idx / DIN_;
  const int d = idx - row * DIN_;
  const int l = row % L_;

  const float w0 = conv_w[d * 4 + 0];
  const float w1 = conv_w[d * 4 + 1];
  const float w2 = conv_w[d * 4 + 2];
  const float w3 = conv_w[d * 4 + 3];

  float s = conv_b[d];
  if (l >= 3) s = fmaf(bf2f(xrb[(size_t)(row - 3) * TWO_DIN_ + d]), w0, s);
  if (l >= 2) s = fmaf(bf2f(xrb[(size_t)(row - 2) * TWO_DIN_ + d]), w1, s);
  if (l >= 1) s = fmaf(bf2f(xrb[(size_t)(row - 1) * TWO_DIN_ + d]), w2, s);
  s = fmaf(bf2f(xrb[(size_t)row * TWO_DIN_ + d]), w3, s);

  const float sig = 1.0f / (1.0f + __expf(-s));
  const float uv = s * sig;
  u[(size_t)row * DIN_ + d] = uv;
  ub[(size_t)row * DIN_ + d] = f2bf(uv);
}

// ---------------------------------------------------------------------------
// delta = softplus(x_dbl[:, :64] @ W_dt + b_dt)
// ---------------------------------------------------------------------------
__global__ __launch_bounds__(256) void delta_kernel(const float* __restrict__ xdbl,
                                                    const float* __restrict__ Wdt,
                                                    const float* __restrict__ bdt,
                                                    float* __restrict__ delta) {
  __shared__ float Xs[8][64];
  const int tid = threadIdx.x;
  const int r0 = blockIdx.x * 8;
  const int d = blockIdx.y * 256 + tid;

  {
    const int i = tid * 2;
    const int r = i >> 6;
    const int k = i & 63;
    Xs[r][k]     = xdbl[(size_t)(r0 + r) * 96 + k];
    Xs[r][k + 1] = xdbl[(size_t)(r0 + r) * 96 + k + 1];
  }
  __syncthreads();

  float acc[8] = {};
  for (int k = 0; k < 64; ++k) {
    const float w = Wdt[(size_t)k * DIN_ + d];
#pragma unroll
    for (int r = 0; r < 8; ++r) acc[r] = fmaf(Xs[r][k], w, acc[r]);
  }
  const float bb = bdt[d];
#pragma unroll
  for (int r = 0; r < 8; ++r) {
    const float v = acc[r] + bb;
    const float sp = fmaxf(v, 0.0f) + log1pf(__expf(-fabsf(v)));
    delta[(size_t)(r0 + r) * DIN_ + d] = sp;
  }
}

// ---------------------------------------------------------------------------
// SSM scan, chunked 3-pass. Aggregates: [b][c][n][d]
// ---------------------------------------------------------------------------
__global__ __launch_bounds__(256) void scan_pass1(const float* __restrict__ delta,
                                                  const float* __restrict__ u,
                                                  const float* __restrict__ xdbl,
                                                  const float* __restrict__ A_log,
                                                  float* __restrict__ Pbuf,
                                                  float* __restrict__ Sbuf) {
  const int d = blockIdx.x * 256 + threadIdx.x;
  const int c = blockIdx.y;
  const int b = blockIdx.z;

  float Areg[N_], P[N_], S[N_];
#pragma unroll
  for (int n = 0; n < N_; ++n) {
    Areg[n] = -__expf(A_log[d * N_ + n]);
    P[n] = 1.0f;
    S[n] = 0.0f;
  }

  const int l0 = c * LC;
  for (int l = l0; l < l0 + LC; ++l) {
    const size_t row = (size_t)b * L_ + l;
    const float dv = delta[row * DIN_ + d];
    const float uv = u[row * DIN_ + d];
    const float du = dv * uv;
    const float* __restrict__ bm = &xdbl[row * 96 + 64];
#pragma unroll
    for (int n = 0; n < N_; ++n) {
      const float a = __expf(dv * Areg[n]);
      P[n] *= a;
      S[n] = fmaf(a, S[n], du * bm[n]);
    }
  }
#pragma unroll
  for (int n = 0; n < N_; ++n) {
    const size_t o = (((size_t)b * CHUNKS + c) * N_ + n) * DIN_ + d;
    Pbuf[o] = P[n];
    Sbuf[o] = S[n];
  }
}

__global__ __launch_bounds__(256) void scan_pass2(const float* __restrict__ Pbuf,
                                                  const float* __restrict__ Sbuf,
                                                  float* __restrict__ Hin) {
  const int d = blockIdx.x * 256 + threadIdx.x;
  const int n = blockIdx.y;
  const int b = blockIdx.z;
  float h = 0.0f;
  for (int c = 0; c < CHUNKS; ++c) {
    const size_t o = (((size_t)b * CHUNKS + c) * N_ + n) * DIN_ + d;
    Hin[o] = h;
    h = fmaf(Pbuf[o], h, Sbuf[o]);
  }
}

__global__ __launch_bounds__(256) void scan_pass3(const float* __restrict__ delta,
                                                  const float* __restrict__ u,
                                                  const float* __restrict__ xdbl,
                                                  const float* __restrict__ A_log,
                                                  const float* __restrict__ Hin,
                                                  const float* __restrict__ Dvec,
                                                  const unsigned short* __restrict__ xrb,
                                                  unsigned short* __restrict__ yb) {
  const int d = blockIdx.x * 256 + threadIdx.x;
  const int c = blockIdx.y;
  const int b = blockIdx.z;

  float Areg[N_], h[N_];
#pragma unroll
  for (int n = 0; n < N_; ++n) {
    Areg[n] = -__expf(A_log[d * N_ + n]);
    h[n] = Hin[(((size_t)b * CHUNKS + c) * N_ + n) * DIN_ + d];
  }
  const float Dd = Dvec[d];

  const int l0 = c * LC;
  for (int l = l0; l < l0 + LC; ++l) {
    const size_t row = (size_t)b * L_ + l;
    const float dv = delta[row * DIN_ + d];
    const float uv = u[row * DIN_ + d];
    const float du = dv * uv;
    const float* __restrict__ xrow = &xdbl[row * 96];
    float acc = 0.0f;
#pragma unroll
    for (int n = 0; n < N_; ++n) {
      const float a = __expf(dv * Areg[n]);
      h[n] = fmaf(a, h[n], du * xrow[64 + n]);   // Bm
      acc = fmaf(h[n], xrow[80 + n], acc);        // Cm
    }
    acc = fmaf(uv, Dd, acc);
    const float resv = bf2f(xrb[row * TWO_DIN_ + DIN_ + d]);
    const float sig = 1.0f / (1.0f + __expf(-resv));
    yb[row * DIN_ + d] = f2bf(acc * (resv * sig));
  }
}

// ---------------------------------------------------------------------------
extern "C" void kernel_launch(void* const* d_in, const int* in_sizes, int n_in,
                              void* d_out, int out_size, void* d_ws, size_t ws_size,
                              hipStream_t stream) {
  const float* x      = (const float*)d_in[0];
  const float* W_in   = (const float*)d_in[1];
  const float* conv_w = (const float*)d_in[2];
  const float* conv_b = (const float*)d_in[3];
  const float* W_x    = (const float*)d_in[4];
  const float* W_dt   = (const float*)d_in[5];
  const float* b_dt   = (const float*)d_in[6];
  const float* W_out  = (const float*)d_in[7];
  const float* A_log  = (const float*)d_in[8];
  const float* Dv     = (const float*)d_in[9];
  float* out = (float*)d_out;

  char* ws = (char*)d_ws;
  // Workspace layout (peak 149.5 MiB <= 153.5 MiB proven in R1):
  unsigned short* xrb   = (unsigned short*)(ws);                 // 32 MB [t1..pass3]
  float* Pout           = (float*)(ws);                          // 32 MB, gemm2 partials (xrb dead)
  float* u              = (float*)(ws + 33554432);               // 32 MB fp32
  unsigned short* ub    = (unsigned short*)(ws + 67108864);      // 16 MB bf16 [conv..xdbl]
  unsigned short* xb    = (unsigned short*)(ws + 83886080);      // 8 MB  [cast..gemm1]
  float* Pxd            = (float*)(ws + 83886080);               // 12.6 MB [xdbl..reduce]
  float* delta          = (float*)(ws + 83886080);               // 32 MB [delta_kernel..pass3]
  float* xdbl           = (float*)(ws + 117440512);              // 1.5 MB
  float* Pbuf           = (float*)(ws + 119013376);              // 8 MB [pass1..pass2]
  float* Sbuf           = (float*)(ws + 127401984);              // 8 MB [pass1..pass2]
  unsigned short* yb    = (unsigned short*)(ws + 119013376);     // 16 MB [pass3..gemm2], aliases P/S
  float* Hin            = (float*)(ws + 135790592);              // 8 MB
  unsigned short* WinT  = (unsigned short*)(ws + 144179200);     // 8 MB
  unsigned short* WoutT = (unsigned short*)(ws + 152567808);     // 4 MB -> ends 156762112

  // 0. casts / transposes
  cast_bf16_kernel<<<(BL_ * DIM_) / (256 * 8), 256, 0, stream>>>(x, xb);
  transpose_cast_kernel<<<dim3(TWO_DIN_ / 32, DIM_ / 32), 256, 0, stream>>>(
      W_in, WinT, DIM_, TWO_DIN_);
  transpose_cast_kernel<<<dim3(DIM_ / 32, DIN_ / 32), 256, 0, stream>>>(
      W_out, WoutT, DIN_, DIM_);
  transpose_cast_kernel<<<dim3(96 / 32, DIN_ / 32), 256, 0, stream>>>(
      W_x, (unsigned short*)(ws + 160956416 - 393216 * 2), DIN_, 96);  // WxT 768KB at tail
  unsigned short* WxT = (unsigned short*)(ws + 160956416 - 393216 * 2);

  // 1. xrb = bf16( x @ W_in )   (4096 x 4096 x 1024), MFMA
  gemm_bf16_mfma<true><<<dim3(TWO_DIN_ / 128, BL_ / 128, 1), 256, 0, stream>>>(
      xb, WinT, xrb, BL_, TWO_DIN_, DIM_, DIM_, DIM_);

  // 2. u = silu(conv(xs) + b), fp32 + bf16
  conv_silu_kernel<<<(BL_ * DIN_) / 256, 256, 0, stream>>>(xrb, conv_w, conv_b, u, ub);

  // 3. x_dbl = u @ W_x via split-K MFMA + reduce
  xdbl_mfma<<<dim3(BL_ / 64, 8), 256, 0, stream>>>(ub, WxT, Pxd);
  reduce_xdbl<<<(BL_ * 96) / 1024, 256, 0, stream>>>(Pxd, xdbl);

  // 4. delta = softplus(x_dbl[:, :64] @ W_dt + b_dt)
  delta_kernel<<<dim3(BL_ / 8, DIN_ / 256), 256, 0, stream>>>(xdbl, W_dt, b_dt, delta);

  // 5-7. chunked SSM scan + gate, y written as bf16
  scan_pass1<<<dim3(DIN_ / 256, CHUNKS, B_), 256, 0, stream>>>(
      delta, u, xdbl, A_log, Pbuf, Sbuf);
  scan_pass2<<<dim3(DIN_ / 256, N_, B_), 256, 0, stream>>>(Pbuf, Sbuf, Hin);
  scan_pass3<<<dim3(DIN_ / 256, CHUNKS, B_), 256, 0, stream>>>(
      delta, u, xdbl, A_log, Hin, Dv, xrb, yb);

  // 8. out = y @ W_out, split-K=2 MFMA (512 concurrent blocks) + combine
  gemm_bf16_mfma<false><<<dim3(DIM_ / 128, BL_ / 128, 2), 256, 0, stream>>>(
      yb, WoutT, Pout, BL_, DIM_, DIN_ / 2, DIN_, DIN_);
  add_out_kernel<<<(BL_ * DIM_) / 1024, 256, 0, stream>>>(Pout, out);
}